// Round 1
// baseline (390.423 us; speedup 1.0000x reference)
//
#include <hip/hip_runtime.h>
#include <hip/hip_bf16.h>
#include <math.h>

typedef __bf16 bf16;
typedef bf16 bf16x8 __attribute__((ext_vector_type(8)));
typedef float f32x4 __attribute__((ext_vector_type(4)));

#define EMB 1024
#define SEQ 2048
#define BATCH 2
#define NH 16
#define HD 64

// ---------------- fp32 -> bf16 convert ----------------
__global__ __launch_bounds__(256) void cvt_f32_bf16(const float* __restrict__ in,
                                                    bf16* __restrict__ out, int n) {
  int i = (blockIdx.x * 256 + threadIdx.x) * 4;
  if (i < n) {
    float4 v = *reinterpret_cast<const float4*>(in + i);
    out[i + 0] = (bf16)v.x;
    out[i + 1] = (bf16)v.y;
    out[i + 2] = (bf16)v.z;
    out[i + 3] = (bf16)v.w;
  }
}

// ---------------- bf16 MFMA GEMM, 128x128 tile, BK=32 ----------------
// A: MxK row-major bf16.  Bm: KxN row-major bf16.  bias: fp32[N].
// mode 0: outF[m*N+n] = acc + bias[n]   (fp32)
// mode 1: QKV scatter: n = which*1024 + h*64 + d ; m = b*2048 + s
//         -> (outQ/outK/outV)[((b*16+h)*2048+s)*64+d] = bf16(acc + bias[n])
#define BM 128
#define BN 128
#define BK 32
#define ASTR 40   // 32 + 8 pad; 80B row stride (multiple of 16B)

__global__ __launch_bounds__(256) void gemm_bf16(
    const bf16* __restrict__ A, const bf16* __restrict__ Bm,
    const float* __restrict__ bias, int M, int N, int K,
    float* __restrict__ outF,
    bf16* __restrict__ outQ, bf16* __restrict__ outK, bf16* __restrict__ outV,
    int mode) {
  __shared__ bf16 Alds[BM][ASTR];
  __shared__ bf16 Blds[BN][ASTR];   // B^T tile: [n][k]

  const int t = threadIdx.x;
  const int lane = t & 63;
  const int w = t >> 6;
  const int wr = w >> 1, wc = w & 1;
  const int lg = lane >> 4, lr = lane & 15;
  const int m0 = blockIdx.y * BM;
  const int n0 = blockIdx.x * BN;

  f32x4 acc[4][4] = {};

  for (int k0 = 0; k0 < K; k0 += BK) {
    __syncthreads();
    // stage A: 128 rows x 32 cols (4 x 16B chunks per row)
    for (int idx = t; idx < 512; idx += 256) {
      int row = idx >> 2, ch = idx & 3;
      bf16x8 v = *reinterpret_cast<const bf16x8*>(
          A + (size_t)(m0 + row) * K + k0 + ch * 8);
      *reinterpret_cast<bf16x8*>(&Alds[row][ch * 8]) = v;
    }
    // stage B^T: read B[k][n] coalesced, scatter to Blds[n][k]
    for (int idx = t; idx < 512; idx += 256) {
      int kk = idx >> 4, ch = idx & 15;
      bf16x8 v = *reinterpret_cast<const bf16x8*>(
          Bm + (size_t)(k0 + kk) * N + n0 + ch * 8);
#pragma unroll
      for (int j = 0; j < 8; ++j) Blds[ch * 8 + j][kk] = v[j];
    }
    __syncthreads();

    bf16x8 af[4], bfr[4];
#pragma unroll
    for (int i = 0; i < 4; ++i)
      af[i] = *reinterpret_cast<const bf16x8*>(&Alds[wr * 64 + i * 16 + lr][lg * 8]);
#pragma unroll
    for (int j = 0; j < 4; ++j)
      bfr[j] = *reinterpret_cast<const bf16x8*>(&Blds[wc * 64 + j * 16 + lr][lg * 8]);
#pragma unroll
    for (int i = 0; i < 4; ++i)
#pragma unroll
      for (int j = 0; j < 4; ++j)
        acc[i][j] = __builtin_amdgcn_mfma_f32_16x16x32_bf16(af[i], bfr[j], acc[i][j], 0, 0, 0);
  }

  // epilogue
#pragma unroll
  for (int i = 0; i < 4; ++i) {
#pragma unroll
    for (int j = 0; j < 4; ++j) {
#pragma unroll
      for (int r = 0; r < 4; ++r) {
        int m = m0 + wr * 64 + i * 16 + lg * 4 + r;
        int n = n0 + wc * 64 + j * 16 + lr;
        float val = acc[i][j][r] + bias[n];
        if (mode == 0) {
          outF[(size_t)m * N + n] = val;
        } else {
          int which = n >> 10, rem = n & 1023;
          int hh = rem >> 6, d = rem & 63;
          int bb = m >> 11, ss = m & 2047;
          size_t o = (((size_t)bb * NH + hh) * SEQ + ss) * HD + d;
          bf16 bv = (bf16)val;
          if (which == 0) outQ[o] = bv;
          else if (which == 1) outK[o] = bv;
          else outV[o] = bv;
        }
      }
    }
  }
}

// ---------------- flash attention, causal ----------------
// Q,K,V: [b][h][s][d] bf16.  Ob: [b][s][h*64+d] bf16 (proj-GEMM A layout)
#define QT 64
#define KT 64
#define VSTR 72   // 64 + 8 pad; 144B row stride (9 x 16B -> aligned b128)

__global__ __launch_bounds__(256) void attn_fwd(
    const bf16* __restrict__ Qb, const bf16* __restrict__ Kb,
    const bf16* __restrict__ Vb, bf16* __restrict__ Ob) {
  __shared__ bf16 Klds[KT][VSTR];
  __shared__ bf16 Vtlds[HD][VSTR];   // V^T: [d][k]
  __shared__ bf16 Plds[QT][VSTR];

  const int t = threadIdx.x;
  const int lane = t & 63;
  const int w = t >> 6;
  const int lg = lane >> 4, lr = lane & 15;
  const int qtile = blockIdx.x;
  const int h = blockIdx.y;
  const int b = blockIdx.z;
  const int qbase = qtile * QT;
  const size_t headoff = ((size_t)b * NH + h) * SEQ * HD;

  // Q fragments held in registers for the whole block
  bf16x8 qf[2];
  {
    int qrow = qbase + w * 16 + lr;
#pragma unroll
    for (int c = 0; c < 2; ++c)
      qf[c] = *reinterpret_cast<const bf16x8*>(
          Qb + headoff + (size_t)qrow * HD + c * 32 + lg * 8);
  }

  float mrow[4], lrow[4];
  f32x4 acco[4];
#pragma unroll
  for (int r = 0; r < 4; ++r) { mrow[r] = -INFINITY; lrow[r] = 0.f; }
#pragma unroll
  for (int dg = 0; dg < 4; ++dg) acco[dg] = (f32x4){0.f, 0.f, 0.f, 0.f};

  const int nkt = qtile + 1;
  for (int kt = 0; kt < nkt; ++kt) {
    const int kbase = kt * KT;
    __syncthreads();
    // stage K tile [64][64]
    for (int idx = t; idx < 512; idx += 256) {
      int row = idx >> 3, ch = idx & 7;
      bf16x8 v = *reinterpret_cast<const bf16x8*>(
          Kb + headoff + (size_t)(kbase + row) * HD + ch * 8);
      *reinterpret_cast<bf16x8*>(&Klds[row][ch * 8]) = v;
    }
    // stage V^T tile [d][k]
    for (int idx = t; idx < 512; idx += 256) {
      int row = idx >> 3, ch = idx & 7;
      bf16x8 v = *reinterpret_cast<const bf16x8*>(
          Vb + headoff + (size_t)(kbase + row) * HD + ch * 8);
#pragma unroll
      for (int j = 0; j < 8; ++j) Vtlds[ch * 8 + j][row] = v[j];
    }
    __syncthreads();

    // QK^T: 4 col-groups x (2 MFMAs over d)
    f32x4 sc[4];
#pragma unroll
    for (int g = 0; g < 4; ++g) {
      sc[g] = (f32x4){0.f, 0.f, 0.f, 0.f};
#pragma unroll
      for (int c = 0; c < 2; ++c) {
        bf16x8 kf = *reinterpret_cast<const bf16x8*>(&Klds[g * 16 + lr][c * 32 + lg * 8]);
        sc[g] = __builtin_amdgcn_mfma_f32_16x16x32_bf16(qf[c], kf, sc[g], 0, 0, 0);
      }
    }
    // scale + causal mask.  q_global row = qbase + w*16 + lg*4 + r
    const int qg0 = qbase + w * 16 + lg * 4;
#pragma unroll
    for (int g = 0; g < 4; ++g) {
      int k_global = kbase + g * 16 + lr;
#pragma unroll
      for (int r = 0; r < 4; ++r) {
        float s = sc[g][r] * 0.125f;
        sc[g][r] = (k_global <= qg0 + r) ? s : -INFINITY;
      }
    }
    // online softmax update (row reduce across lanes 0..15 of each group)
    float newm[4], corr[4];
#pragma unroll
    for (int r = 0; r < 4; ++r) {
      float mx = fmaxf(fmaxf(sc[0][r], sc[1][r]), fmaxf(sc[2][r], sc[3][r]));
      mx = fmaxf(mx, __shfl_xor(mx, 1));
      mx = fmaxf(mx, __shfl_xor(mx, 2));
      mx = fmaxf(mx, __shfl_xor(mx, 4));
      mx = fmaxf(mx, __shfl_xor(mx, 8));
      newm[r] = fmaxf(mrow[r], mx);
      corr[r] = expf(mrow[r] - newm[r]);
      mrow[r] = newm[r];
    }
#pragma unroll
    for (int r = 0; r < 4; ++r) {
      float rs = 0.f;
#pragma unroll
      for (int g = 0; g < 4; ++g) {
        float p = expf(sc[g][r] - newm[r]);   // masked -> exp(-inf)=0
        rs += p;
        Plds[w * 16 + lg * 4 + r][g * 16 + lr] = (bf16)p;
      }
      rs += __shfl_xor(rs, 1);
      rs += __shfl_xor(rs, 2);
      rs += __shfl_xor(rs, 4);
      rs += __shfl_xor(rs, 8);
      lrow[r] = lrow[r] * corr[r] + rs;
#pragma unroll
      for (int dg = 0; dg < 4; ++dg) acco[dg][r] *= corr[r];
    }
    // PV: O[16][64] += P[16][64] * V[64][64]
#pragma unroll
    for (int dg = 0; dg < 4; ++dg) {
#pragma unroll
      for (int c = 0; c < 2; ++c) {
        bf16x8 pf = *reinterpret_cast<const bf16x8*>(&Plds[w * 16 + lr][c * 32 + lg * 8]);
        bf16x8 vf = *reinterpret_cast<const bf16x8*>(&Vtlds[dg * 16 + lr][c * 32 + lg * 8]);
        acco[dg] = __builtin_amdgcn_mfma_f32_16x16x32_bf16(pf, vf, acco[dg], 0, 0, 0);
      }
    }
  }

  // normalize + write [b][s][h*64+d]
#pragma unroll
  for (int r = 0; r < 4; ++r) {
    float inv = 1.0f / lrow[r];
    int q = qbase + w * 16 + lg * 4 + r;
#pragma unroll
    for (int dg = 0; dg < 4; ++dg) {
      int d = h * HD + dg * 16 + lr;
      Ob[((size_t)b * SEQ + q) * EMB + d] = (bf16)(acco[dg][r] * inv);
    }
  }
}

// ---------------- launch ----------------
extern "C" void kernel_launch(void* const* d_in, const int* in_sizes, int n_in,
                              void* d_out, int out_size, void* d_ws, size_t ws_size,
                              hipStream_t stream) {
  const float* x    = (const float*)d_in[0];
  const float* Wqkv = (const float*)d_in[1];
  const float* bqkv = (const float*)d_in[2];
  const float* Wout = (const float*)d_in[3];
  const float* bout = (const float*)d_in[4];
  float* out = (float*)d_out;

  char* ws = (char*)d_ws;
  bf16* xb    = (bf16*)(ws);                      // 4096*1024  -> 8 MiB
  bf16* wqkvb = (bf16*)(ws + 8388608);            // 1024*3072  -> 6 MiB
  bf16* woutb = (bf16*)(ws + 14680064);           // 1024*1024  -> 2 MiB
  bf16* Qb    = (bf16*)(ws + 16777216);           // 2*16*2048*64 -> 8 MiB
  bf16* Kb    = (bf16*)(ws + 25165824);
  bf16* Vb    = (bf16*)(ws + 33554432);
  bf16* attnb = (bf16*)(ws + 41943040);           // 4096*1024 -> 8 MiB

  const int n1 = 4096 * 1024, n2 = 1024 * 3072, n3 = 1024 * 1024;
  cvt_f32_bf16<<<(n1 / 4 + 255) / 256, 256, 0, stream>>>(x, xb, n1);
  cvt_f32_bf16<<<(n2 / 4 + 255) / 256, 256, 0, stream>>>(Wqkv, wqkvb, n2);
  cvt_f32_bf16<<<(n3 / 4 + 255) / 256, 256, 0, stream>>>(Wout, woutb, n3);

  dim3 g1(3072 / BN, 4096 / BM);   // 24 x 32
  gemm_bf16<<<g1, 256, 0, stream>>>(xb, wqkvb, bqkv, 4096, 3072, 1024,
                                    nullptr, Qb, Kb, Vb, 1);

  dim3 ga(SEQ / QT, NH, BATCH);    // 32 x 16 x 2
  attn_fwd<<<ga, 256, 0, stream>>>(Qb, Kb, Vb, attnb);

  dim3 g2(1024 / BN, 4096 / BM);   // 8 x 32
  gemm_bf16<<<g2, 256, 0, stream>>>(attnb, woutb, bout, 4096, 1024, 1024,
                                    out, nullptr, nullptr, nullptr, 0);
}

// Round 2
// 177.476 us; speedup vs baseline: 2.1999x; 2.1999x over previous
//
#include <hip/hip_runtime.h>
#include <hip/hip_bf16.h>
#include <math.h>

typedef __bf16 bf16;
typedef bf16 bf16x4 __attribute__((ext_vector_type(4)));
typedef bf16 bf16x8 __attribute__((ext_vector_type(8)));
typedef float f32x4 __attribute__((ext_vector_type(4)));

#define EMB 1024
#define SEQ 2048
#define BATCH 2
#define NH 16
#define HD 64

// async global->LDS, 16B per lane (dest = wave-uniform base + lane*16)
__device__ __forceinline__ void glds16(const void* g, void* l) {
  __builtin_amdgcn_global_load_lds(
      (__attribute__((address_space(1))) void*)g,
      (__attribute__((address_space(3))) void*)l, 16, 0, 0);
}

// ---------------- fp32 -> bf16 convert ----------------
__global__ __launch_bounds__(256) void cvt_f32_bf16(const float* __restrict__ in,
                                                    bf16* __restrict__ out, int n) {
  int i = (blockIdx.x * 256 + threadIdx.x) * 4;
  if (i < n) {
    float4 v = *reinterpret_cast<const float4*>(in + i);
    out[i + 0] = (bf16)v.x;
    out[i + 1] = (bf16)v.y;
    out[i + 2] = (bf16)v.z;
    out[i + 3] = (bf16)v.w;
  }
}

// ---------------- fp32 -> bf16 transpose (W[k][n] -> Wt[n][k]) ----------------
__global__ __launch_bounds__(256) void transpose_cvt(const float* __restrict__ in,
                                                     bf16* __restrict__ out,
                                                     int R, int C) {
  __shared__ float tile[32][33];
  int c0 = blockIdx.x * 32, r0 = blockIdx.y * 32;
  int tx = threadIdx.x, ty = threadIdx.y;  // 32 x 8
#pragma unroll
  for (int i = 0; i < 32; i += 8)
    tile[ty + i][tx] = in[(size_t)(r0 + ty + i) * C + c0 + tx];
  __syncthreads();
#pragma unroll
  for (int i = 0; i < 32; i += 8)
    out[(size_t)(c0 + ty + i) * R + r0 + tx] = (bf16)tile[tx][ty + i];
}

// ---------------- bf16 MFMA GEMM (m97 structure), 128x128 tile, BK=32 ----------------
// A: MxK row-major bf16.  Bt: NxK row-major bf16 (B pre-transposed).  bias: fp32[N].
// mode 0: outF[m*N+n] = acc + bias[n]   (fp32)
// mode 1: QKV scatter. n = which*1024 + h*64 + d ; m = b*2048 + s
//   Q,K -> [b][h][s][d] bf16 ;  V -> Vt [b][h][d][s] bf16 (transposed, packed x4)
#define BM 128
#define BN 128
#define BK 32

__global__ __launch_bounds__(256) void gemm_bf16(
    const bf16* __restrict__ A, const bf16* __restrict__ Bt,
    const float* __restrict__ bias, int M, int N, int K,
    float* __restrict__ outF,
    bf16* __restrict__ outQ, bf16* __restrict__ outK, bf16* __restrict__ outVt,
    int mode) {
  __shared__ bf16 Alds[BM][BK];   // linear, unpadded (global_load_lds dest)
  __shared__ bf16 Blds[BN][BK];

  const int t = threadIdx.x;
  const int lane = t & 63;
  const int w = t >> 6;
  const int wr = w >> 1, wc = w & 1;
  const int lg = lane >> 4, lr = lane & 15;
  const int m0 = blockIdx.y * BM;
  const int n0 = blockIdx.x * BN;

  // chunk ids (16B each; 512 chunks per 8KB tile; 2 per thread per matrix)
  const int c0 = w * 64 + lane;
  const int c1 = 256 + w * 64 + lane;
  const int r0 = c0 >> 2, ch0 = c0 & 3;
  const int r1 = c1 >> 2, ch1 = c1 & 3;

  f32x4 acc[4][4] = {};

  for (int k0 = 0; k0 < K; k0 += BK) {
    __syncthreads();
    glds16(A + (size_t)(m0 + r0) * K + k0 + ch0 * 8, &Alds[0][0] + c0 * 8);
    glds16(A + (size_t)(m0 + r1) * K + k0 + ch1 * 8, &Alds[0][0] + c1 * 8);
    glds16(Bt + (size_t)(n0 + r0) * K + k0 + ch0 * 8, &Blds[0][0] + c0 * 8);
    glds16(Bt + (size_t)(n0 + r1) * K + k0 + ch1 * 8, &Blds[0][0] + c1 * 8);
    __syncthreads();

    bf16x8 af[4], bfr[4];
#pragma unroll
    for (int i = 0; i < 4; ++i)
      af[i] = *reinterpret_cast<const bf16x8*>(&Alds[wr * 64 + i * 16 + lr][lg * 8]);
#pragma unroll
    for (int j = 0; j < 4; ++j)
      bfr[j] = *reinterpret_cast<const bf16x8*>(&Blds[wc * 64 + j * 16 + lr][lg * 8]);
#pragma unroll
    for (int i = 0; i < 4; ++i)
#pragma unroll
      for (int j = 0; j < 4; ++j)
        acc[i][j] = __builtin_amdgcn_mfma_f32_16x16x32_bf16(af[i], bfr[j], acc[i][j], 0, 0, 0);
  }

  // epilogue
#pragma unroll
  for (int j = 0; j < 4; ++j) {
    const int n = n0 + wc * 64 + j * 16 + lr;
    const float bi = bias[n];
#pragma unroll
    for (int i = 0; i < 4; ++i) {
      const int mb = m0 + wr * 64 + i * 16 + lg * 4;
      if (mode == 0) {
#pragma unroll
        for (int r = 0; r < 4; ++r)
          outF[(size_t)(mb + r) * N + n] = acc[i][j][r] + bi;
      } else {
        const int which = n >> 10, rem = n & 1023;
        const int hh = rem >> 6, d = rem & 63;
        const int bb = mb >> 11, ss = mb & 2047;
        if (which == 2) {
          bf16x4 pv;
#pragma unroll
          for (int r = 0; r < 4; ++r) pv[r] = (bf16)(acc[i][j][r] + bi);
          *reinterpret_cast<bf16x4*>(
              outVt + (((size_t)bb * NH + hh) * HD + d) * SEQ + ss) = pv;
        } else {
          bf16* dst = (which == 0 ? outQ : outK) +
                      (((size_t)bb * NH + hh) * SEQ + ss) * HD + d;
#pragma unroll
          for (int r = 0; r < 4; ++r) dst[(size_t)r * HD] = (bf16)(acc[i][j][r] + bi);
        }
      }
    }
  }
}

// ---------------- flash attention, causal ----------------
// Qb,Kb: [b][h][s][d] bf16.  Vt: [b][h][d][s] bf16.  Ob: [b][s][h*64+d] bf16
#define QT 64
#define KT 64
#define VSTR 72   // 64 + 8 pad; 144B row stride

#define SCALE2 0.1803368801111244f   // (1/8) * log2(e)

__global__ __launch_bounds__(256) void attn_fwd(
    const bf16* __restrict__ Qb, const bf16* __restrict__ Kb,
    const bf16* __restrict__ Vt, bf16* __restrict__ Ob) {
  __shared__ bf16 Klds[KT][VSTR];
  __shared__ bf16 Vtlds[HD][VSTR];   // [d][k]
  __shared__ bf16 Plds[QT][VSTR];

  const int t = threadIdx.x;
  const int lane = t & 63;
  const int w = t >> 6;
  const int lg = lane >> 4, lr = lane & 15;
  // LPT ordering: largest qtile first (causal imbalance)
  const int id = blockIdx.x;
  const int qtile = 31 - (id >> 5);
  const int hb = id & 31;
  const int h = hb & 15, b = hb >> 4;
  const int qbase = qtile * QT;
  const size_t headoff = ((size_t)b * NH + h) * SEQ * HD;   // == headoffT

  bf16x8 qf[2];
  {
    int qrow = qbase + w * 16 + lr;
#pragma unroll
    for (int c = 0; c < 2; ++c)
      qf[c] = *reinterpret_cast<const bf16x8*>(
          Qb + headoff + (size_t)qrow * HD + c * 32 + lg * 8);
  }

  float mrow[4], lrow[4];
  f32x4 acco[4];
#pragma unroll
  for (int r = 0; r < 4; ++r) { mrow[r] = -INFINITY; lrow[r] = 0.f; }
#pragma unroll
  for (int dg = 0; dg < 4; ++dg) acco[dg] = (f32x4){0.f, 0.f, 0.f, 0.f};

  const int nkt = qtile + 1;
  for (int kt = 0; kt < nkt; ++kt) {
    const int kbase = kt * KT;
    __syncthreads();
    // stage K tile [64][64] and V^T tile [64][64] — pure vector loads/writes
    for (int idx = t; idx < 1024; idx += 256) {
      int which = idx >> 9, rem = idx & 511;
      int row = rem >> 3, ch = rem & 7;
      if (which == 0) {
        bf16x8 v = *reinterpret_cast<const bf16x8*>(
            Kb + headoff + (size_t)(kbase + row) * HD + ch * 8);
        *reinterpret_cast<bf16x8*>(&Klds[row][ch * 8]) = v;
      } else {
        bf16x8 v = *reinterpret_cast<const bf16x8*>(
            Vt + headoff + (size_t)row * SEQ + kbase + ch * 8);
        *reinterpret_cast<bf16x8*>(&Vtlds[row][ch * 8]) = v;
      }
    }
    __syncthreads();

    // QK^T: 4 col-groups x (2 MFMAs over d), pre-scaled into log2 domain
    f32x4 sc[4];
#pragma unroll
    for (int g = 0; g < 4; ++g) {
      sc[g] = (f32x4){0.f, 0.f, 0.f, 0.f};
#pragma unroll
      for (int c = 0; c < 2; ++c) {
        bf16x8 kf = *reinterpret_cast<const bf16x8*>(&Klds[g * 16 + lr][c * 32 + lg * 8]);
        sc[g] = __builtin_amdgcn_mfma_f32_16x16x32_bf16(qf[c], kf, sc[g], 0, 0, 0);
      }
    }
    const int qg0 = qbase + w * 16 + lg * 4;
    if (kt == nkt - 1) {
      // only the diagonal tile needs the causal mask (wave-uniform branch)
#pragma unroll
      for (int g = 0; g < 4; ++g) {
        int k_global = kbase + g * 16 + lr;
#pragma unroll
        for (int r = 0; r < 4; ++r) {
          float s = sc[g][r] * SCALE2;
          sc[g][r] = (k_global <= qg0 + r) ? s : -INFINITY;
        }
      }
    } else {
#pragma unroll
      for (int g = 0; g < 4; ++g)
#pragma unroll
        for (int r = 0; r < 4; ++r) sc[g][r] *= SCALE2;
    }
    // online softmax (log2 domain), row-reduce across 16 lanes
    float newm[4], corr[4];
#pragma unroll
    for (int r = 0; r < 4; ++r) {
      float mx = fmaxf(fmaxf(sc[0][r], sc[1][r]), fmaxf(sc[2][r], sc[3][r]));
      mx = fmaxf(mx, __shfl_xor(mx, 1));
      mx = fmaxf(mx, __shfl_xor(mx, 2));
      mx = fmaxf(mx, __shfl_xor(mx, 4));
      mx = fmaxf(mx, __shfl_xor(mx, 8));
      newm[r] = fmaxf(mrow[r], mx);
      corr[r] = exp2f(mrow[r] - newm[r]);
      mrow[r] = newm[r];
    }
#pragma unroll
    for (int r = 0; r < 4; ++r) {
      float rs = 0.f;
#pragma unroll
      for (int g = 0; g < 4; ++g) {
        float p = exp2f(sc[g][r] - newm[r]);
        rs += p;
        Plds[w * 16 + lg * 4 + r][g * 16 + lr] = (bf16)p;
      }
      rs += __shfl_xor(rs, 1);
      rs += __shfl_xor(rs, 2);
      rs += __shfl_xor(rs, 4);
      rs += __shfl_xor(rs, 8);
      lrow[r] = lrow[r] * corr[r] + rs;
#pragma unroll
      for (int dg = 0; dg < 4; ++dg) acco[dg][r] *= corr[r];
    }
    // PV: O[16][64] += P[16][64] * V[64][64]
#pragma unroll
    for (int c = 0; c < 2; ++c) {
      bf16x8 pf = *reinterpret_cast<const bf16x8*>(&Plds[w * 16 + lr][c * 32 + lg * 8]);
#pragma unroll
      for (int dg = 0; dg < 4; ++dg) {
        bf16x8 vf = *reinterpret_cast<const bf16x8*>(&Vtlds[dg * 16 + lr][c * 32 + lg * 8]);
        acco[dg] = __builtin_amdgcn_mfma_f32_16x16x32_bf16(pf, vf, acco[dg], 0, 0, 0);
      }
    }
  }

  // normalize + write [b][s][h*64+d]
#pragma unroll
  for (int r = 0; r < 4; ++r) {
    float inv = 1.0f / lrow[r];
    int q = qbase + w * 16 + lg * 4 + r;
#pragma unroll
    for (int dg = 0; dg < 4; ++dg) {
      int d = h * HD + dg * 16 + lr;
      Ob[((size_t)b * SEQ + q) * EMB + d] = (bf16)(acco[dg][r] * inv);
    }
  }
}

// ---------------- launch ----------------
extern "C" void kernel_launch(void* const* d_in, const int* in_sizes, int n_in,
                              void* d_out, int out_size, void* d_ws, size_t ws_size,
                              hipStream_t stream) {
  const float* x    = (const float*)d_in[0];
  const float* Wqkv = (const float*)d_in[1];
  const float* bqkv = (const float*)d_in[2];
  const float* Wout = (const float*)d_in[3];
  const float* bout = (const float*)d_in[4];
  float* out = (float*)d_out;

  char* ws = (char*)d_ws;
  bf16* xb     = (bf16*)(ws);                      // 4096x1024   8 MiB
  bf16* wqkvt  = (bf16*)(ws + 8388608);            // 3072x1024   6 MiB (W_qkv^T)
  bf16* woutt  = (bf16*)(ws + 14680064);           // 1024x1024   2 MiB (W_out^T)
  bf16* Qb     = (bf16*)(ws + 16777216);           // [b][h][s][d] 8 MiB
  bf16* Kb     = (bf16*)(ws + 25165824);           // [b][h][s][d] 8 MiB
  bf16* Vtb    = (bf16*)(ws + 33554432);           // [b][h][d][s] 8 MiB
  bf16* attnb  = (bf16*)(ws + 41943040);           // 4096x1024   8 MiB

  const int n1 = 4096 * 1024;
  cvt_f32_bf16<<<(n1 / 4 + 255) / 256, 256, 0, stream>>>(x, xb, n1);
  dim3 tb(32, 8);
  transpose_cvt<<<dim3(3072 / 32, 1024 / 32), tb, 0, stream>>>(Wqkv, wqkvt, 1024, 3072);
  transpose_cvt<<<dim3(1024 / 32, 1024 / 32), tb, 0, stream>>>(Wout, woutt, 1024, 1024);

  dim3 g1(3072 / BN, 4096 / BM);   // 24 x 32
  gemm_bf16<<<g1, 256, 0, stream>>>(xb, wqkvt, bqkv, 4096, 3072, 1024,
                                    nullptr, Qb, Kb, Vtb, 1);

  attn_fwd<<<1024, 256, 0, stream>>>(Qb, Kb, Vtb, attnb);

  dim3 g2(1024 / BN, 4096 / BM);   // 8 x 32
  gemm_bf16<<<g2, 256, 0, stream>>>(attnb, woutt, bout, 4096, 1024, 1024,
                                    out, nullptr, nullptr, nullptr, 0);
}

// Round 3
// 156.629 us; speedup vs baseline: 2.4927x; 1.1331x over previous
//
#include <hip/hip_runtime.h>
#include <hip/hip_bf16.h>
#include <math.h>

typedef __bf16 bf16;
typedef bf16 bf16x4 __attribute__((ext_vector_type(4)));
typedef bf16 bf16x8 __attribute__((ext_vector_type(8)));
typedef float f32x4 __attribute__((ext_vector_type(4)));
typedef float f32x16 __attribute__((ext_vector_type(16)));
typedef unsigned int uint;

#define EMB 1024
#define SEQ 2048
#define BATCH 2
#define NH 16
#define HD 64

#define SCALE2 0.18033688011112042f   // (1/8) * log2(e), folded into Q

// async global->LDS, 16B per lane (dest = wave-uniform base + lane*16)
__device__ __forceinline__ void glds16(const void* g, void* l) {
  __builtin_amdgcn_global_load_lds(
      (__attribute__((address_space(1))) void*)g,
      (__attribute__((address_space(3))) void*)l, 16, 0, 0);
}

// pack two f32 -> packed bf16 pair (lo=src0, hi=src1)
__device__ __forceinline__ uint cvtpk(float lo, float hi) {
  uint r;
  asm("v_cvt_pk_bf16_f32 %0, %1, %2" : "=v"(r) : "v"(lo), "v"(hi));
  return r;
}
// v_permlane32_swap_b32: a <- [a.row0, b.row0], b <- [a.row1, b.row1]
__device__ __forceinline__ void plswap(uint& a, uint& b) {
  asm("v_permlane32_swap_b32 %0, %1" : "+v"(a), "+v"(b));
}

// ---------------- fp32 -> bf16 convert ----------------
__global__ __launch_bounds__(256) void cvt_f32_bf16(const float* __restrict__ in,
                                                    bf16* __restrict__ out, int n) {
  int i = (blockIdx.x * 256 + threadIdx.x) * 4;
  if (i < n) {
    float4 v = *reinterpret_cast<const float4*>(in + i);
    out[i + 0] = (bf16)v.x;
    out[i + 1] = (bf16)v.y;
    out[i + 2] = (bf16)v.z;
    out[i + 3] = (bf16)v.w;
  }
}

// ---------------- fp32 -> bf16 transpose (W[k][n] -> Wt[n][k]) ----------------
__global__ __launch_bounds__(256) void transpose_cvt(const float* __restrict__ in,
                                                     bf16* __restrict__ out,
                                                     int R, int C) {
  __shared__ float tile[32][33];
  int c0 = blockIdx.x * 32, r0 = blockIdx.y * 32;
  int tx = threadIdx.x, ty = threadIdx.y;  // 32 x 8
#pragma unroll
  for (int i = 0; i < 32; i += 8)
    tile[ty + i][tx] = in[(size_t)(r0 + ty + i) * C + c0 + tx];
  __syncthreads();
#pragma unroll
  for (int i = 0; i < 32; i += 8)
    out[(size_t)(c0 + ty + i) * R + r0 + tx] = (bf16)tile[tx][ty + i];
}

// ---------------- bf16 MFMA GEMM (m97 structure), 128x128 tile, BK=32 ----------------
// mode 0: outF[m*N+n] = acc + bias[n]
// mode 1: QKV scatter. Q (scaled by SCALE2), K -> [b][h][s][d]; V -> Vt [b][h][d][s]
#define BM 128
#define BN 128
#define BK 32

__global__ __launch_bounds__(256) void gemm_bf16(
    const bf16* __restrict__ A, const bf16* __restrict__ Bt,
    const float* __restrict__ bias, int M, int N, int K,
    float* __restrict__ outF,
    bf16* __restrict__ outQ, bf16* __restrict__ outK, bf16* __restrict__ outVt,
    int mode) {
  __shared__ bf16 Alds[BM][BK];
  __shared__ bf16 Blds[BN][BK];

  const int t = threadIdx.x;
  const int lane = t & 63;
  const int w = t >> 6;
  const int wr = w >> 1, wc = w & 1;
  const int lg = lane >> 4, lr = lane & 15;
  const int m0 = blockIdx.y * BM;
  const int n0 = blockIdx.x * BN;

  const int c0 = w * 64 + lane;
  const int c1 = 256 + w * 64 + lane;
  const int r0 = c0 >> 2, ch0 = c0 & 3;
  const int r1 = c1 >> 2, ch1 = c1 & 3;

  f32x4 acc[4][4] = {};

  for (int k0 = 0; k0 < K; k0 += BK) {
    __syncthreads();
    glds16(A + (size_t)(m0 + r0) * K + k0 + ch0 * 8, &Alds[0][0] + c0 * 8);
    glds16(A + (size_t)(m0 + r1) * K + k0 + ch1 * 8, &Alds[0][0] + c1 * 8);
    glds16(Bt + (size_t)(n0 + r0) * K + k0 + ch0 * 8, &Blds[0][0] + c0 * 8);
    glds16(Bt + (size_t)(n0 + r1) * K + k0 + ch1 * 8, &Blds[0][0] + c1 * 8);
    __syncthreads();

    bf16x8 af[4], bfr[4];
#pragma unroll
    for (int i = 0; i < 4; ++i)
      af[i] = *reinterpret_cast<const bf16x8*>(&Alds[wr * 64 + i * 16 + lr][lg * 8]);
#pragma unroll
    for (int j = 0; j < 4; ++j)
      bfr[j] = *reinterpret_cast<const bf16x8*>(&Blds[wc * 64 + j * 16 + lr][lg * 8]);
#pragma unroll
    for (int i = 0; i < 4; ++i)
#pragma unroll
      for (int j = 0; j < 4; ++j)
        acc[i][j] = __builtin_amdgcn_mfma_f32_16x16x32_bf16(af[i], bfr[j], acc[i][j], 0, 0, 0);
  }

#pragma unroll
  for (int j = 0; j < 4; ++j) {
    const int n = n0 + wc * 64 + j * 16 + lr;
    const float bi = bias[n];
#pragma unroll
    for (int i = 0; i < 4; ++i) {
      const int mb = m0 + wr * 64 + i * 16 + lg * 4;
      if (mode == 0) {
#pragma unroll
        for (int r = 0; r < 4; ++r)
          outF[(size_t)(mb + r) * N + n] = acc[i][j][r] + bi;
      } else {
        const int which = n >> 10, rem = n & 1023;
        const int hh = rem >> 6, d = rem & 63;
        const int bb = mb >> 11, ss = mb & 2047;
        if (which == 2) {
          bf16x4 pv;
#pragma unroll
          for (int r = 0; r < 4; ++r) pv[r] = (bf16)(acc[i][j][r] + bi);
          *reinterpret_cast<bf16x4*>(
              outVt + (((size_t)bb * NH + hh) * HD + d) * SEQ + ss) = pv;
        } else if (which == 0) {
          bf16* dst = outQ + (((size_t)bb * NH + hh) * SEQ + ss) * HD + d;
#pragma unroll
          for (int r = 0; r < 4; ++r)
            dst[(size_t)r * HD] = (bf16)((acc[i][j][r] + bi) * SCALE2);
        } else {
          bf16* dst = outK + (((size_t)bb * NH + hh) * SEQ + ss) * HD + d;
#pragma unroll
          for (int r = 0; r < 4; ++r) dst[(size_t)r * HD] = (bf16)(acc[i][j][r] + bi);
        }
      }
    }
  }
}

// ---------------- flash attention: 1 wave per 32 q-rows, all in-register ----------------
// Qb,Kb: [b][h][s][d] bf16 (Q pre-scaled).  Vt: [b][h][d][s] bf16.
// Ob: [b][s][h*64+d] bf16.
// Swapped QK^T: S^T = mfma(K, Q): lane q = lane&31, k = (reg&3)+8*(reg>>2)+4*hi (+32 for s1).
// Swapped PV:   O^T = mfma(V^T, P^T): lane q = lane&31, d = (reg&3)+8*(reg>>2)+4*hi (+32).
__global__ __launch_bounds__(64, 2) void attn_fwd(
    const bf16* __restrict__ Qb, const bf16* __restrict__ Kb,
    const bf16* __restrict__ Vt, bf16* __restrict__ Ob) {
  const int lane = threadIdx.x;
  const int l31 = lane & 31;
  const int hi = lane >> 5;
  const int hi8 = hi << 3;
  const int id = blockIdx.x;
  const int qw = 63 - (id >> 5);        // LPT: longest q-tiles dispatched first
  const int bh = id & 31;
  const int h = bh & 15, b = bh >> 4;
  const size_t headoff = ((size_t)b * NH + h) * SEQ * HD;
  const int qbase = qw << 5;

  // Q fragments (B-operand): col q = l31, contraction d = dstep*16 + hi8 + j
  bf16x8 qf[4];
  {
    const bf16* qr = Qb + headoff + (size_t)(qbase + l31) * HD + hi8;
#pragma unroll
    for (int d = 0; d < 4; ++d) qf[d] = *reinterpret_cast<const bf16x8*>(qr + d * 16);
  }

  f32x16 accO0 = {}, accO1 = {};        // O^T: d 0..31 / 32..63, col q = l31
  float m = -1e30f, lsum = 0.f;
  const int nkt = (qbase >> 6) + 1;

  for (int kt = 0; kt < nkt; ++kt) {
    const int kb = kt << 6;
    // ---- QK^T (swapped): A = K rows, B = Q ----
    f32x16 s0 = {}, s1 = {};
    {
      const bf16* kr0 = Kb + headoff + (size_t)(kb + l31) * HD + hi8;
      const bf16* kr1 = kr0 + 32 * HD;
#pragma unroll
      for (int d = 0; d < 4; ++d) {
        bf16x8 kf0 = *reinterpret_cast<const bf16x8*>(kr0 + d * 16);
        bf16x8 kf1 = *reinterpret_cast<const bf16x8*>(kr1 + d * 16);
        s0 = __builtin_amdgcn_mfma_f32_32x32x16_bf16(kf0, qf[d], s0, 0, 0, 0);
        s1 = __builtin_amdgcn_mfma_f32_32x32x16_bf16(kf1, qf[d], s1, 0, 0, 0);
      }
    }
    // ---- causal mask (diagonal tile only; wave-uniform branch) ----
    if (kt == nkt - 1) {
      const int kq = kb + hi * 4 - (qbase + l31);   // k - q = kq + off (+32 for s1)
#pragma unroll
      for (int r = 0; r < 16; ++r) {
        const int off = (r & 3) + 8 * (r >> 2);
        if (kq + off > 0) s0[r] = -1e30f;
        if (kq + off + 32 > 0) s1[r] = -1e30f;
      }
    }
    // ---- online softmax (log2 domain), lane-local row ----
    float pm[16];
#pragma unroll
    for (int r = 0; r < 16; ++r) pm[r] = fmaxf(s0[r], s1[r]);
#pragma unroll
    for (int st = 8; st > 0; st >>= 1)
#pragma unroll
      for (int r = 0; r < st; ++r) pm[r] = fmaxf(pm[r], pm[r + st]);
    const float tm = fmaxf(pm[0], __shfl_xor(pm[0], 32));
    const float newm = fmaxf(m, tm);
    const float corr = __builtin_amdgcn_exp2f(m - newm);
    m = newm;
#pragma unroll
    for (int r = 0; r < 16; ++r) {
      s0[r] = __builtin_amdgcn_exp2f(s0[r] - newm);
      s1[r] = __builtin_amdgcn_exp2f(s1[r] - newm);
    }
    float ps[16];
#pragma unroll
    for (int r = 0; r < 16; ++r) ps[r] = s0[r] + s1[r];
#pragma unroll
    for (int st = 8; st > 0; st >>= 1)
#pragma unroll
      for (int r = 0; r < st; ++r) ps[r] += ps[r + st];
    const float rs = ps[0] + __shfl_xor(ps[0], 32);
    lsum = lsum * corr + rs;
    accO0 *= corr;
    accO1 *= corr;
    // ---- P -> bf16 B-fragments (T12: cvt_pk + permlane32_swap) ----
    uint wv[16];
    wv[0]  = cvtpk(s0[0],  s0[1]);  wv[1]  = cvtpk(s0[2],  s0[3]);
    wv[2]  = cvtpk(s0[4],  s0[5]);  wv[3]  = cvtpk(s0[6],  s0[7]);
    wv[4]  = cvtpk(s0[8],  s0[9]);  wv[5]  = cvtpk(s0[10], s0[11]);
    wv[6]  = cvtpk(s0[12], s0[13]); wv[7]  = cvtpk(s0[14], s0[15]);
    wv[8]  = cvtpk(s1[0],  s1[1]);  wv[9]  = cvtpk(s1[2],  s1[3]);
    wv[10] = cvtpk(s1[4],  s1[5]);  wv[11] = cvtpk(s1[6],  s1[7]);
    wv[12] = cvtpk(s1[8],  s1[9]);  wv[13] = cvtpk(s1[10], s1[11]);
    wv[14] = cvtpk(s1[12], s1[13]); wv[15] = cvtpk(s1[14], s1[15]);
    plswap(wv[0], wv[2]);  plswap(wv[1], wv[3]);
    plswap(wv[4], wv[6]);  plswap(wv[5], wv[7]);
    plswap(wv[8], wv[10]); plswap(wv[9], wv[11]);
    plswap(wv[12], wv[14]); plswap(wv[13], wv[15]);
    // ---- PV (swapped): A = V^T rows (d), B = P^T ----
    {
      const bf16* vr0 = Vt + headoff + (size_t)l31 * SEQ + kb + hi8;
      const bf16* vr1 = vr0 + (size_t)32 * SEQ;
#pragma unroll
      for (int ks = 0; ks < 4; ++ks) {
        uint4 u = make_uint4(wv[ks * 4], wv[ks * 4 + 1], wv[ks * 4 + 2], wv[ks * 4 + 3]);
        bf16x8 pf = *reinterpret_cast<bf16x8*>(&u);
        bf16x8 vf0 = *reinterpret_cast<const bf16x8*>(vr0 + ks * 16);
        bf16x8 vf1 = *reinterpret_cast<const bf16x8*>(vr1 + ks * 16);
        accO0 = __builtin_amdgcn_mfma_f32_32x32x16_bf16(vf0, pf, accO0, 0, 0, 0);
        accO1 = __builtin_amdgcn_mfma_f32_32x32x16_bf16(vf1, pf, accO1, 0, 0, 0);
      }
    }
  }

  // ---- epilogue: normalize + write O[b][q][h*64+d] ----
  const float inv = 1.0f / lsum;
  bf16* orow = Ob + ((size_t)b * SEQ + qbase + l31) * EMB + h * HD + hi * 4;
#pragma unroll
  for (int rq = 0; rq < 4; ++rq) {
    bf16x4 o0, o1;
#pragma unroll
    for (int i = 0; i < 4; ++i) {
      o0[i] = (bf16)(accO0[rq * 4 + i] * inv);
      o1[i] = (bf16)(accO1[rq * 4 + i] * inv);
    }
    *reinterpret_cast<bf16x4*>(orow + rq * 8) = o0;
    *reinterpret_cast<bf16x4*>(orow + 32 + rq * 8) = o1;
  }
}

// ---------------- launch ----------------
extern "C" void kernel_launch(void* const* d_in, const int* in_sizes, int n_in,
                              void* d_out, int out_size, void* d_ws, size_t ws_size,
                              hipStream_t stream) {
  const float* x    = (const float*)d_in[0];
  const float* Wqkv = (const float*)d_in[1];
  const float* bqkv = (const float*)d_in[2];
  const float* Wout = (const float*)d_in[3];
  const float* bout = (const float*)d_in[4];
  float* out = (float*)d_out;

  char* ws = (char*)d_ws;
  bf16* xb     = (bf16*)(ws);                      // 4096x1024   8 MiB
  bf16* wqkvt  = (bf16*)(ws + 8388608);            // 3072x1024   6 MiB (W_qkv^T)
  bf16* woutt  = (bf16*)(ws + 14680064);           // 1024x1024   2 MiB (W_out^T)
  bf16* Qb     = (bf16*)(ws + 16777216);           // [b][h][s][d] 8 MiB (pre-scaled)
  bf16* Kb     = (bf16*)(ws + 25165824);           // [b][h][s][d] 8 MiB
  bf16* Vtb    = (bf16*)(ws + 33554432);           // [b][h][d][s] 8 MiB
  bf16* attnb  = (bf16*)(ws + 41943040);           // 4096x1024   8 MiB

  const int n1 = 4096 * 1024;
  cvt_f32_bf16<<<(n1 / 4 + 255) / 256, 256, 0, stream>>>(x, xb, n1);
  dim3 tb(32, 8);
  transpose_cvt<<<dim3(3072 / 32, 1024 / 32), tb, 0, stream>>>(Wqkv, wqkvt, 1024, 3072);
  transpose_cvt<<<dim3(1024 / 32, 1024 / 32), tb, 0, stream>>>(Wout, woutt, 1024, 1024);

  dim3 g1(3072 / BN, 4096 / BM);   // 24 x 32
  gemm_bf16<<<g1, 256, 0, stream>>>(xb, wqkvt, bqkv, 4096, 3072, 1024,
                                    nullptr, Qb, Kb, Vtb, 1);

  attn_fwd<<<2048, 64, 0, stream>>>(Qb, Kb, Vtb, attnb);

  dim3 g2(1024 / BN, 4096 / BM);   // 8 x 32
  gemm_bf16<<<g2, 256, 0, stream>>>(attnb, woutt, bout, 4096, 1024, 1024,
                                    out, nullptr, nullptr, nullptr, 0);
}

// Round 4
// 156.604 us; speedup vs baseline: 2.4931x; 1.0002x over previous
//
#include <hip/hip_runtime.h>
#include <hip/hip_bf16.h>
#include <math.h>

typedef __bf16 bf16;
typedef bf16 bf16x4 __attribute__((ext_vector_type(4)));
typedef bf16 bf16x8 __attribute__((ext_vector_type(8)));
typedef float f32x4 __attribute__((ext_vector_type(4)));
typedef float f32x16 __attribute__((ext_vector_type(16)));
typedef unsigned int uint;

#define EMB 1024
#define SEQ 2048
#define BATCH 2
#define NH 16
#define HD 64

#define SCALE2 0.18033688011112042f   // (1/8) * log2(e), folded into Q

// async global->LDS, 16B per lane (dest = wave-uniform base + lane*16)
__device__ __forceinline__ void glds16(const void* g, void* l) {
  __builtin_amdgcn_global_load_lds(
      (__attribute__((address_space(1))) void*)g,
      (__attribute__((address_space(3))) void*)l, 16, 0, 0);
}

// pack two f32 -> packed bf16 pair (lo=src0, hi=src1)
__device__ __forceinline__ uint cvtpk(float lo, float hi) {
  uint r;
  asm("v_cvt_pk_bf16_f32 %0, %1, %2" : "=v"(r) : "v"(lo), "v"(hi));
  return r;
}
// v_permlane32_swap_b32: a <- [a.row0, b.row0], b <- [a.row1, b.row1]
__device__ __forceinline__ void plswap(uint& a, uint& b) {
  asm("v_permlane32_swap_b32 %0, %1" : "+v"(a), "+v"(b));
}

// ---------------- fp32 -> bf16 convert ----------------
__global__ __launch_bounds__(256) void cvt_f32_bf16(const float* __restrict__ in,
                                                    bf16* __restrict__ out, int n) {
  int i = (blockIdx.x * 256 + threadIdx.x) * 4;
  if (i < n) {
    float4 v = *reinterpret_cast<const float4*>(in + i);
    out[i + 0] = (bf16)v.x;
    out[i + 1] = (bf16)v.y;
    out[i + 2] = (bf16)v.z;
    out[i + 3] = (bf16)v.w;
  }
}

// ---------------- fp32 -> bf16 transpose (W[k][n] -> Wt[n][k]) ----------------
__global__ __launch_bounds__(256) void transpose_cvt(const float* __restrict__ in,
                                                     bf16* __restrict__ out,
                                                     int R, int C) {
  __shared__ float tile[32][33];
  int c0 = blockIdx.x * 32, r0 = blockIdx.y * 32;
  int tx = threadIdx.x, ty = threadIdx.y;  // 32 x 8
#pragma unroll
  for (int i = 0; i < 32; i += 8)
    tile[ty + i][tx] = in[(size_t)(r0 + ty + i) * C + c0 + tx];
  __syncthreads();
#pragma unroll
  for (int i = 0; i < 32; i += 8)
    out[(size_t)(c0 + ty + i) * R + r0 + tx] = (bf16)tile[tx][ty + i];
}

// ---------------- bf16 MFMA GEMM (m97 structure), 128x128 tile, BK=32 ----------------
// mode 0: outF[m*N+n] = acc + bias[n]
// mode 1: QKV scatter. Q (scaled by SCALE2), K -> [b][h][s][d]; V -> Vt [b][h][d][s]
#define BM 128
#define BN 128
#define BK 32

__global__ __launch_bounds__(256) void gemm_bf16(
    const bf16* __restrict__ A, const bf16* __restrict__ Bt,
    const float* __restrict__ bias, int M, int N, int K,
    float* __restrict__ outF,
    bf16* __restrict__ outQ, bf16* __restrict__ outK, bf16* __restrict__ outVt,
    int mode) {
  __shared__ bf16 Alds[BM][BK];
  __shared__ bf16 Blds[BN][BK];

  const int t = threadIdx.x;
  const int lane = t & 63;
  const int w = t >> 6;
  const int wr = w >> 1, wc = w & 1;
  const int lg = lane >> 4, lr = lane & 15;
  const int m0 = blockIdx.y * BM;
  const int n0 = blockIdx.x * BN;

  const int c0 = w * 64 + lane;
  const int c1 = 256 + w * 64 + lane;
  const int r0 = c0 >> 2, ch0 = c0 & 3;
  const int r1 = c1 >> 2, ch1 = c1 & 3;

  f32x4 acc[4][4] = {};

  for (int k0 = 0; k0 < K; k0 += BK) {
    __syncthreads();
    glds16(A + (size_t)(m0 + r0) * K + k0 + ch0 * 8, &Alds[0][0] + c0 * 8);
    glds16(A + (size_t)(m0 + r1) * K + k0 + ch1 * 8, &Alds[0][0] + c1 * 8);
    glds16(Bt + (size_t)(n0 + r0) * K + k0 + ch0 * 8, &Blds[0][0] + c0 * 8);
    glds16(Bt + (size_t)(n0 + r1) * K + k0 + ch1 * 8, &Blds[0][0] + c1 * 8);
    __syncthreads();

    bf16x8 af[4], bfr[4];
#pragma unroll
    for (int i = 0; i < 4; ++i)
      af[i] = *reinterpret_cast<const bf16x8*>(&Alds[wr * 64 + i * 16 + lr][lg * 8]);
#pragma unroll
    for (int j = 0; j < 4; ++j)
      bfr[j] = *reinterpret_cast<const bf16x8*>(&Blds[wc * 64 + j * 16 + lr][lg * 8]);
#pragma unroll
    for (int i = 0; i < 4; ++i)
#pragma unroll
      for (int j = 0; j < 4; ++j)
        acc[i][j] = __builtin_amdgcn_mfma_f32_16x16x32_bf16(af[i], bfr[j], acc[i][j], 0, 0, 0);
  }

#pragma unroll
  for (int j = 0; j < 4; ++j) {
    const int n = n0 + wc * 64 + j * 16 + lr;
    const float bi = bias[n];
#pragma unroll
    for (int i = 0; i < 4; ++i) {
      const int mb = m0 + wr * 64 + i * 16 + lg * 4;
      if (mode == 0) {
#pragma unroll
        for (int r = 0; r < 4; ++r)
          outF[(size_t)(mb + r) * N + n] = acc[i][j][r] + bi;
      } else {
        const int which = n >> 10, rem = n & 1023;
        const int hh = rem >> 6, d = rem & 63;
        const int bb = mb >> 11, ss = mb & 2047;
        if (which == 2) {
          bf16x4 pv;
#pragma unroll
          for (int r = 0; r < 4; ++r) pv[r] = (bf16)(acc[i][j][r] + bi);
          *reinterpret_cast<bf16x4*>(
              outVt + (((size_t)bb * NH + hh) * HD + d) * SEQ + ss) = pv;
        } else if (which == 0) {
          bf16* dst = outQ + (((size_t)bb * NH + hh) * SEQ + ss) * HD + d;
#pragma unroll
          for (int r = 0; r < 4; ++r)
            dst[(size_t)r * HD] = (bf16)((acc[i][j][r] + bi) * SCALE2);
        } else {
          bf16* dst = outK + (((size_t)bb * NH + hh) * SEQ + ss) * HD + d;
#pragma unroll
          for (int r = 0; r < 4; ++r) dst[(size_t)r * HD] = (bf16)(acc[i][j][r] + bi);
        }
      }
    }
  }
}

// ---------------- flash attention: 1 wave per 32 q-rows, in-register, ----------------
// ---------------- reg-double-buffered K/V prefetch (T14) + defer-max (T13) ----------
// Qb,Kb: [b][h][s][d] bf16 (Q pre-scaled).  Vt: [b][h][d][s] bf16.
// Ob: [b][s][h*64+d] bf16.
// Swapped QK^T: S^T = mfma(K, Q): lane q = lane&31, k = (reg&3)+8*(reg>>2)+4*hi (+32 for s1).
// Swapped PV:   O^T = mfma(V^T, P^T): lane q = lane&31, d = (reg&3)+8*(reg>>2)+4*hi (+32).

// One K/V tile step. KC/VC: current-tile fragments (consumed). KN/VN: next-tile
// fragments (loaded here, consumed next call). All indices compile-time constant.
#define ATTN_TILE(KC, VC, KN, VN)                                              \
  {                                                                            \
    const int kb = kt << 6;                                                    \
    const int kbn = (kt + 1 < nkt) ? kb + 64 : kb;                             \
    const bf16* krn = Kbase + (size_t)kbn * HD;                                \
    const bf16* vrn = Vbase + kbn;                                             \
    _Pragma("unroll")                                                          \
    for (int dd = 0; dd < 4; ++dd) {                                           \
      KN[dd]     = *reinterpret_cast<const bf16x8*>(krn + dd * 16);            \
      KN[4 + dd] = *reinterpret_cast<const bf16x8*>(krn + 32 * HD + dd * 16);  \
      VN[dd]     = *reinterpret_cast<const bf16x8*>(vrn + dd * 16);            \
      VN[4 + dd] = *reinterpret_cast<const bf16x8*>(vrn + (size_t)32 * SEQ + dd * 16); \
    }                                                                          \
    f32x16 s0 = {}, s1 = {};                                                   \
    _Pragma("unroll")                                                          \
    for (int dd = 0; dd < 4; ++dd) {                                           \
      s0 = __builtin_amdgcn_mfma_f32_32x32x16_bf16(KC[dd], qf[dd], s0, 0, 0, 0);       \
      s1 = __builtin_amdgcn_mfma_f32_32x32x16_bf16(KC[4 + dd], qf[dd], s1, 0, 0, 0);   \
    }                                                                          \
    if (kt == nkt - 1) {                                                       \
      const int kq = kb + hi * 4 - qrow;                                       \
      _Pragma("unroll")                                                        \
      for (int r = 0; r < 16; ++r) {                                           \
        const int off = (r & 3) + 8 * (r >> 2);                                \
        if (kq + off > 0) s0[r] = -1e30f;                                      \
        if (kq + off + 32 > 0) s1[r] = -1e30f;                                 \
      }                                                                        \
    }                                                                          \
    float pm[16];                                                              \
    _Pragma("unroll")                                                          \
    for (int r = 0; r < 16; ++r) pm[r] = fmaxf(s0[r], s1[r]);                  \
    _Pragma("unroll")                                                          \
    for (int st = 8; st > 0; st >>= 1) {                                       \
      _Pragma("unroll")                                                        \
      for (int r = 0; r < st; ++r) pm[r] = fmaxf(pm[r], pm[r + st]);           \
    }                                                                          \
    const float tm = fmaxf(pm[0], __shfl_xor(pm[0], 32));                      \
    if (!__all(tm <= m + 8.f)) {                                               \
      const float newm = fmaxf(m, tm);                                         \
      const float corr = __builtin_amdgcn_exp2f(m - newm);                     \
      m = newm;                                                                \
      lsum *= corr;                                                            \
      accO0 *= corr;                                                           \
      accO1 *= corr;                                                           \
    }                                                                          \
    _Pragma("unroll")                                                          \
    for (int r = 0; r < 16; ++r) {                                             \
      s0[r] = __builtin_amdgcn_exp2f(s0[r] - m);                               \
      s1[r] = __builtin_amdgcn_exp2f(s1[r] - m);                               \
    }                                                                          \
    float ps[16];                                                              \
    _Pragma("unroll")                                                          \
    for (int r = 0; r < 16; ++r) ps[r] = s0[r] + s1[r];                        \
    _Pragma("unroll")                                                          \
    for (int st = 8; st > 0; st >>= 1) {                                       \
      _Pragma("unroll")                                                        \
      for (int r = 0; r < st; ++r) ps[r] += ps[r + st];                        \
    }                                                                          \
    lsum += ps[0] + __shfl_xor(ps[0], 32);                                     \
    uint wv[16];                                                               \
    wv[0]  = cvtpk(s0[0],  s0[1]);  wv[1]  = cvtpk(s0[2],  s0[3]);             \
    wv[2]  = cvtpk(s0[4],  s0[5]);  wv[3]  = cvtpk(s0[6],  s0[7]);             \
    wv[4]  = cvtpk(s0[8],  s0[9]);  wv[5]  = cvtpk(s0[10], s0[11]);            \
    wv[6]  = cvtpk(s0[12], s0[13]); wv[7]  = cvtpk(s0[14], s0[15]);            \
    wv[8]  = cvtpk(s1[0],  s1[1]);  wv[9]  = cvtpk(s1[2],  s1[3]);             \
    wv[10] = cvtpk(s1[4],  s1[5]);  wv[11] = cvtpk(s1[6],  s1[7]);             \
    wv[12] = cvtpk(s1[8],  s1[9]);  wv[13] = cvtpk(s1[10], s1[11]);            \
    wv[14] = cvtpk(s1[12], s1[13]); wv[15] = cvtpk(s1[14], s1[15]);            \
    plswap(wv[0], wv[2]);   plswap(wv[1], wv[3]);                              \
    plswap(wv[4], wv[6]);   plswap(wv[5], wv[7]);                              \
    plswap(wv[8], wv[10]);  plswap(wv[9], wv[11]);                             \
    plswap(wv[12], wv[14]); plswap(wv[13], wv[15]);                            \
    _Pragma("unroll")                                                          \
    for (int ks = 0; ks < 4; ++ks) {                                           \
      uint4 u = make_uint4(wv[ks * 4], wv[ks * 4 + 1], wv[ks * 4 + 2], wv[ks * 4 + 3]); \
      bf16x8 pf = *reinterpret_cast<bf16x8*>(&u);                              \
      accO0 = __builtin_amdgcn_mfma_f32_32x32x16_bf16(VC[ks], pf, accO0, 0, 0, 0);     \
      accO1 = __builtin_amdgcn_mfma_f32_32x32x16_bf16(VC[4 + ks], pf, accO1, 0, 0, 0); \
    }                                                                          \
  }

__global__ __launch_bounds__(64, 2) void attn_fwd(
    const bf16* __restrict__ Qb, const bf16* __restrict__ Kb,
    const bf16* __restrict__ Vt, bf16* __restrict__ Ob) {
  const int lane = threadIdx.x;
  const int l31 = lane & 31;
  const int hi = lane >> 5;
  const int hi8 = hi << 3;
  const int id = blockIdx.x;
  const int qw = 63 - (id >> 5);        // LPT: longest q-tiles dispatched first
  const int bh = id & 31;
  const int h = bh & 15, b = bh >> 4;
  const size_t headoff = ((size_t)b * NH + h) * SEQ * HD;
  const int qbase = qw << 5;
  const int qrow = qbase + l31;

  // Q fragments (B-operand): col q = l31, contraction d = dstep*16 + hi8 + j
  bf16x8 qf[4];
  {
    const bf16* qr = Qb + headoff + (size_t)qrow * HD + hi8;
#pragma unroll
    for (int d = 0; d < 4; ++d) qf[d] = *reinterpret_cast<const bf16x8*>(qr + d * 16);
  }

  const bf16* Kbase = Kb + headoff + (size_t)l31 * HD + hi8;   // + kb*HD per tile
  const bf16* Vbase = Vt + headoff + (size_t)l31 * SEQ + hi8;  // + kb per tile

  f32x16 accO0 = {}, accO1 = {};        // O^T: d 0..31 / 32..63, col q = l31
  float m = -1e30f, lsum = 0.f;
  const int nkt = (qbase >> 6) + 1;

  bf16x8 kA[8], vA[8], kB[8], vB[8];
  // prefetch tile 0 into A
  {
    const bf16* kr0 = Kbase;
    const bf16* vr0 = Vbase;
#pragma unroll
    for (int dd = 0; dd < 4; ++dd) {
      kA[dd]     = *reinterpret_cast<const bf16x8*>(kr0 + dd * 16);
      kA[4 + dd] = *reinterpret_cast<const bf16x8*>(kr0 + 32 * HD + dd * 16);
      vA[dd]     = *reinterpret_cast<const bf16x8*>(vr0 + dd * 16);
      vA[4 + dd] = *reinterpret_cast<const bf16x8*>(vr0 + (size_t)32 * SEQ + dd * 16);
    }
  }

  int kt = 0;
  for (;;) {
    ATTN_TILE(kA, vA, kB, vB);
    if (++kt == nkt) break;
    ATTN_TILE(kB, vB, kA, vA);
    if (++kt == nkt) break;
  }

  // ---- epilogue: normalize + write O[b][q][h*64+d] ----
  const float inv = 1.0f / lsum;
  bf16* orow = Ob + ((size_t)b * SEQ + qrow) * EMB + h * HD + hi * 4;
#pragma unroll
  for (int rq = 0; rq < 4; ++rq) {
    bf16x4 o0, o1;
#pragma unroll
    for (int i = 0; i < 4; ++i) {
      o0[i] = (bf16)(accO0[rq * 4 + i] * inv);
      o1[i] = (bf16)(accO1[rq * 4 + i] * inv);
    }
    *reinterpret_cast<bf16x4*>(orow + rq * 8) = o0;
    *reinterpret_cast<bf16x4*>(orow + 32 + rq * 8) = o1;
  }
}

// ---------------- launch ----------------
extern "C" void kernel_launch(void* const* d_in, const int* in_sizes, int n_in,
                              void* d_out, int out_size, void* d_ws, size_t ws_size,
                              hipStream_t stream) {
  const float* x    = (const float*)d_in[0];
  const float* Wqkv = (const float*)d_in[1];
  const float* bqkv = (const float*)d_in[2];
  const float* Wout = (const float*)d_in[3];
  const float* bout = (const float*)d_in[4];
  float* out = (float*)d_out;

  char* ws = (char*)d_ws;
  bf16* xb     = (bf16*)(ws);                      // 4096x1024   8 MiB
  bf16* wqkvt  = (bf16*)(ws + 8388608);            // 3072x1024   6 MiB (W_qkv^T)
  bf16* woutt  = (bf16*)(ws + 14680064);           // 1024x1024   2 MiB (W_out^T)
  bf16* Qb     = (bf16*)(ws + 16777216);           // [b][h][s][d] 8 MiB (pre-scaled)
  bf16* Kb     = (bf16*)(ws + 25165824);           // [b][h][s][d] 8 MiB
  bf16* Vtb    = (bf16*)(ws + 33554432);           // [b][h][d][s] 8 MiB
  bf16* attnb  = (bf16*)(ws + 41943040);           // 4096x1024   8 MiB

  const int n1 = 4096 * 1024;
  cvt_f32_bf16<<<(n1 / 4 + 255) / 256, 256, 0, stream>>>(x, xb, n1);
  dim3 tb(32, 8);
  transpose_cvt<<<dim3(3072 / 32, 1024 / 32), tb, 0, stream>>>(Wqkv, wqkvt, 1024, 3072);
  transpose_cvt<<<dim3(1024 / 32, 1024 / 32), tb, 0, stream>>>(Wout, woutt, 1024, 1024);

  dim3 g1(3072 / BN, 4096 / BM);   // 24 x 32
  gemm_bf16<<<g1, 256, 0, stream>>>(xb, wqkvt, bqkv, 4096, 3072, 1024,
                                    nullptr, Qb, Kb, Vtb, 1);

  attn_fwd<<<2048, 64, 0, stream>>>(Qb, Kb, Vtb, attnb);

  dim3 g2(1024 / BN, 4096 / BM);   // 8 x 32
  gemm_bf16<<<g2, 256, 0, stream>>>(attnb, woutt, bout, 4096, 1024, 1024,
                                    out, nullptr, nullptr, nullptr, 0);
}

// Round 5
// 127.769 us; speedup vs baseline: 3.0557x; 1.2257x over previous
//
#include <hip/hip_runtime.h>
#include <hip/hip_bf16.h>
#include <math.h>

typedef __bf16 bf16;
typedef bf16 bf16x4 __attribute__((ext_vector_type(4)));
typedef bf16 bf16x8 __attribute__((ext_vector_type(8)));
typedef float f32x4 __attribute__((ext_vector_type(4)));
typedef float f32x16 __attribute__((ext_vector_type(16)));
typedef unsigned int uint;

#define EMB 1024
#define SEQ 2048
#define BATCH 2
#define NH 16
#define HD 64

#define SCALE2 0.18033688011112042f   // (1/8) * log2(e), folded into Q

// async global->LDS, 16B per lane (dest = wave-uniform base + lane*16)
__device__ __forceinline__ void glds16(const void* g, void* l) {
  __builtin_amdgcn_global_load_lds(
      (__attribute__((address_space(1))) void*)g,
      (__attribute__((address_space(3))) void*)l, 16, 0, 0);
}

// pack two f32 -> packed bf16 pair (lo=src0, hi=src1)
__device__ __forceinline__ uint cvtpk(float lo, float hi) {
  uint r;
  asm("v_cvt_pk_bf16_f32 %0, %1, %2" : "=v"(r) : "v"(lo), "v"(hi));
  return r;
}
// v_permlane32_swap_b32: a <- [a.row0, b.row0], b <- [a.row1, b.row1]
__device__ __forceinline__ void plswap(uint& a, uint& b) {
  asm("v_permlane32_swap_b32 %0, %1" : "+v"(a), "+v"(b));
}

// ---------------- fp32 -> bf16 convert ----------------
__global__ __launch_bounds__(256) void cvt_f32_bf16(const float* __restrict__ in,
                                                    bf16* __restrict__ out, int n) {
  int i = (blockIdx.x * 256 + threadIdx.x) * 4;
  if (i < n) {
    float4 v = *reinterpret_cast<const float4*>(in + i);
    out[i + 0] = (bf16)v.x;
    out[i + 1] = (bf16)v.y;
    out[i + 2] = (bf16)v.z;
    out[i + 3] = (bf16)v.w;
  }
}

// ---------------- fp32 -> bf16 transpose (W[k][n] -> Wt[n][k]) ----------------
__global__ __launch_bounds__(256) void transpose_cvt(const float* __restrict__ in,
                                                     bf16* __restrict__ out,
                                                     int R, int C) {
  __shared__ float tile[32][33];
  int c0 = blockIdx.x * 32, r0 = blockIdx.y * 32;
  int tx = threadIdx.x, ty = threadIdx.y;  // 32 x 8
#pragma unroll
  for (int i = 0; i < 32; i += 8)
    tile[ty + i][tx] = in[(size_t)(r0 + ty + i) * C + c0 + tx];
  __syncthreads();
#pragma unroll
  for (int i = 0; i < 32; i += 8)
    out[(size_t)(c0 + ty + i) * R + r0 + tx] = (bf16)tile[tx][ty + i];
}

// ---------------- bf16 MFMA GEMM (m97 structure), 128x128 tile, BK=32 ----------------
// mode 0: outF[m*N+n] = acc + bias[n]
// mode 1: QKV scatter. Q (scaled by SCALE2), K -> [b][h][s][d]; V -> Vt [b][h][d][s]
#define BM 128
#define BN 128
#define BK 32

__global__ __launch_bounds__(256) void gemm_bf16(
    const bf16* __restrict__ A, const bf16* __restrict__ Bt,
    const float* __restrict__ bias, int M, int N, int K,
    float* __restrict__ outF,
    bf16* __restrict__ outQ, bf16* __restrict__ outK, bf16* __restrict__ outVt,
    int mode) {
  __shared__ bf16 Alds[BM][BK];
  __shared__ bf16 Blds[BN][BK];

  const int t = threadIdx.x;
  const int lane = t & 63;
  const int w = t >> 6;
  const int wr = w >> 1, wc = w & 1;
  const int lg = lane >> 4, lr = lane & 15;
  const int m0 = blockIdx.y * BM;
  const int n0 = blockIdx.x * BN;

  const int c0 = w * 64 + lane;
  const int c1 = 256 + w * 64 + lane;
  const int r0 = c0 >> 2, ch0 = c0 & 3;
  const int r1 = c1 >> 2, ch1 = c1 & 3;

  f32x4 acc[4][4] = {};

  for (int k0 = 0; k0 < K; k0 += BK) {
    __syncthreads();
    glds16(A + (size_t)(m0 + r0) * K + k0 + ch0 * 8, &Alds[0][0] + c0 * 8);
    glds16(A + (size_t)(m0 + r1) * K + k0 + ch1 * 8, &Alds[0][0] + c1 * 8);
    glds16(Bt + (size_t)(n0 + r0) * K + k0 + ch0 * 8, &Blds[0][0] + c0 * 8);
    glds16(Bt + (size_t)(n0 + r1) * K + k0 + ch1 * 8, &Blds[0][0] + c1 * 8);
    __syncthreads();

    bf16x8 af[4], bfr[4];
#pragma unroll
    for (int i = 0; i < 4; ++i)
      af[i] = *reinterpret_cast<const bf16x8*>(&Alds[wr * 64 + i * 16 + lr][lg * 8]);
#pragma unroll
    for (int j = 0; j < 4; ++j)
      bfr[j] = *reinterpret_cast<const bf16x8*>(&Blds[wc * 64 + j * 16 + lr][lg * 8]);
#pragma unroll
    for (int i = 0; i < 4; ++i)
#pragma unroll
      for (int j = 0; j < 4; ++j)
        acc[i][j] = __builtin_amdgcn_mfma_f32_16x16x32_bf16(af[i], bfr[j], acc[i][j], 0, 0, 0);
  }

#pragma unroll
  for (int j = 0; j < 4; ++j) {
    const int n = n0 + wc * 64 + j * 16 + lr;
    const float bi = bias[n];
#pragma unroll
    for (int i = 0; i < 4; ++i) {
      const int mb = m0 + wr * 64 + i * 16 + lg * 4;
      if (mode == 0) {
#pragma unroll
        for (int r = 0; r < 4; ++r)
          outF[(size_t)(mb + r) * N + n] = acc[i][j][r] + bi;
      } else {
        const int which = n >> 10, rem = n & 1023;
        const int hh = rem >> 6, d = rem & 63;
        const int bb = mb >> 11, ss = mb & 2047;
        if (which == 2) {
          bf16x4 pv;
#pragma unroll
          for (int r = 0; r < 4; ++r) pv[r] = (bf16)(acc[i][j][r] + bi);
          *reinterpret_cast<bf16x4*>(
              outVt + (((size_t)bb * NH + hh) * HD + d) * SEQ + ss) = pv;
        } else if (which == 0) {
          bf16* dst = outQ + (((size_t)bb * NH + hh) * SEQ + ss) * HD + d;
#pragma unroll
          for (int r = 0; r < 4; ++r)
            dst[(size_t)r * HD] = (bf16)((acc[i][j][r] + bi) * SCALE2);
        } else {
          bf16* dst = outK + (((size_t)bb * NH + hh) * SEQ + ss) * HD + d;
#pragma unroll
          for (int r = 0; r < 4; ++r) dst[(size_t)r * HD] = (bf16)(acc[i][j][r] + bi);
        }
      }
    }
  }
}

// ---------------- flash attention: 4-wave blocks, LDS-shared K/V, ----------------
// swapped-operand 32x32 MFMA, in-register softmax (T12) + defer-max (T13).
// Qb,Kb: [b][h][s][d] bf16 (Q pre-scaled).  Vt: [b][h][d][s] bf16.
// Ob: [b][s][h*64+d] bf16.
// LDS tiles [64 rows][64 elems=128B], chunk-swizzled: physical chunk = c ^ (row&7)
// (achieved by pre-swizzling the per-lane GLOBAL source; LDS dest stays linear).

// stage K/V tile kt_ into LDS buffer buf_ (per-wave: 2 K chunks-of-1KB + 2 V)
#define STAGE(kt_, buf_)                                                       \
  {                                                                            \
    const int kb_ = (kt_) << 6;                                                \
    _Pragma("unroll")                                                          \
    for (int j = 0; j < 2; ++j) {                                              \
      const int g = (w * 2 + j) * 64 + lane;                                   \
      const int row = g >> 3, cc = g & 7;                                      \
      const int pc = (cc ^ (row & 7)) << 3;                                    \
      glds16(Kb + headoff + (size_t)(kb_ + row) * HD + pc, &Kl[buf_][g * 8]);  \
      glds16(Vt + headoff + (size_t)row * SEQ + kb_ + pc, &Vl[buf_][g * 8]);   \
    }                                                                          \
  }

__global__ __launch_bounds__(256, 2) void attn_fwd(
    const bf16* __restrict__ Qb, const bf16* __restrict__ Kb,
    const bf16* __restrict__ Vt, bf16* __restrict__ Ob) {
  __shared__ bf16 Kl[2][64 * 64];
  __shared__ bf16 Vl[2][64 * 64];

  const int t = threadIdx.x;
  const int lane = t & 63;
  const int w = t >> 6;
  const int l31 = lane & 31;
  const int hi = lane >> 5;
  const int hi8 = hi << 3;
  const int swz = l31 & 7;

  // balanced pairing: ids 0..255 -> qb 15..8, ids 256..511 -> qb 0..7
  const int id = blockIdx.x;
  const int qb = (id < 256) ? (15 - (id >> 5)) : ((id - 256) >> 5);
  const int bh = id & 31;
  const int h = bh & 15, b = bh >> 4;
  const size_t headoff = ((size_t)b * NH + h) * SEQ * HD;
  const int qbase_w = qb * 128 + w * 32;
  const int qrow = qbase_w + l31;

  // Q fragments (B-operand): col q = l31, contraction d = dd*16 + hi8 + j
  bf16x8 qf[4];
  {
    const bf16* qr = Qb + headoff + (size_t)qrow * HD + hi8;
#pragma unroll
    for (int d = 0; d < 4; ++d) qf[d] = *reinterpret_cast<const bf16x8*>(qr + d * 16);
  }

  f32x16 accO0 = {}, accO1 = {};        // O^T: d 0..31 / 32..63, col q = l31
  float m = -1e30f, lsum = 0.f;
  const int my_nkt = ((qbase_w + 31) >> 6) + 1;   // wave's causal tile count
  const int blk_nkt = qb * 2 + 2;                 // block's tile count

  STAGE(0, 0);
  __syncthreads();

  for (int kt = 0; kt < blk_nkt; ++kt) {
    const int cur = kt & 1;
    if (kt + 1 < blk_nkt) STAGE(kt + 1, cur ^ 1);

    if (kt < my_nkt) {
      const int kb = kt << 6;
      // ---- QK^T (swapped): A = K rows from LDS, B = Q ----
      f32x16 s0 = {}, s1 = {};
#pragma unroll
      for (int dd = 0; dd < 4; ++dd) {
        const int pc = ((dd * 2 + hi) ^ swz) << 3;
        bf16x8 kf0 = *reinterpret_cast<const bf16x8*>(&Kl[cur][l31 * 64 + pc]);
        bf16x8 kf1 = *reinterpret_cast<const bf16x8*>(&Kl[cur][(l31 + 32) * 64 + pc]);
        s0 = __builtin_amdgcn_mfma_f32_32x32x16_bf16(kf0, qf[dd], s0, 0, 0, 0);
        s1 = __builtin_amdgcn_mfma_f32_32x32x16_bf16(kf1, qf[dd], s1, 0, 0, 0);
      }
      // ---- causal mask (wave's diagonal tile only) ----
      if (kt == my_nkt - 1) {
        const int kq = kb + hi * 4 - qrow;
#pragma unroll
        for (int r = 0; r < 16; ++r) {
          const int off = (r & 3) + 8 * (r >> 2);
          if (kq + off > 0) s0[r] = -1e30f;
          if (kq + off + 32 > 0) s1[r] = -1e30f;
        }
      }
      // ---- online softmax (log2 domain), lane-local row ----
      float pm[16];
#pragma unroll
      for (int r = 0; r < 16; ++r) pm[r] = fmaxf(s0[r], s1[r]);
#pragma unroll
      for (int st = 8; st > 0; st >>= 1)
#pragma unroll
        for (int r = 0; r < st; ++r) pm[r] = fmaxf(pm[r], pm[r + st]);
      const float tm = fmaxf(pm[0], __shfl_xor(pm[0], 32));
      if (!__all(tm <= m + 8.f)) {
        const float newm = fmaxf(m, tm);
        const float corr = __builtin_amdgcn_exp2f(m - newm);
        m = newm;
        lsum *= corr;
        accO0 *= corr;
        accO1 *= corr;
      }
#pragma unroll
      for (int r = 0; r < 16; ++r) {
        s0[r] = __builtin_amdgcn_exp2f(s0[r] - m);
        s1[r] = __builtin_amdgcn_exp2f(s1[r] - m);
      }
      float ps[16];
#pragma unroll
      for (int r = 0; r < 16; ++r) ps[r] = s0[r] + s1[r];
#pragma unroll
      for (int st = 8; st > 0; st >>= 1)
#pragma unroll
        for (int r = 0; r < st; ++r) ps[r] += ps[r + st];
      lsum += ps[0] + __shfl_xor(ps[0], 32);
      // ---- P -> bf16 B-fragments (T12: cvt_pk + permlane32_swap) ----
      uint wv[16];
      wv[0]  = cvtpk(s0[0],  s0[1]);  wv[1]  = cvtpk(s0[2],  s0[3]);
      wv[2]  = cvtpk(s0[4],  s0[5]);  wv[3]  = cvtpk(s0[6],  s0[7]);
      wv[4]  = cvtpk(s0[8],  s0[9]);  wv[5]  = cvtpk(s0[10], s0[11]);
      wv[6]  = cvtpk(s0[12], s0[13]); wv[7]  = cvtpk(s0[14], s0[15]);
      wv[8]  = cvtpk(s1[0],  s1[1]);  wv[9]  = cvtpk(s1[2],  s1[3]);
      wv[10] = cvtpk(s1[4],  s1[5]);  wv[11] = cvtpk(s1[6],  s1[7]);
      wv[12] = cvtpk(s1[8],  s1[9]);  wv[13] = cvtpk(s1[10], s1[11]);
      wv[14] = cvtpk(s1[12], s1[13]); wv[15] = cvtpk(s1[14], s1[15]);
      plswap(wv[0], wv[2]);   plswap(wv[1], wv[3]);
      plswap(wv[4], wv[6]);   plswap(wv[5], wv[7]);
      plswap(wv[8], wv[10]);  plswap(wv[9], wv[11]);
      plswap(wv[12], wv[14]); plswap(wv[13], wv[15]);
      // ---- PV (swapped): A = V^T rows (d) from LDS, B = P^T ----
#pragma unroll
      for (int ks = 0; ks < 4; ++ks) {
        uint4 u = make_uint4(wv[ks * 4], wv[ks * 4 + 1], wv[ks * 4 + 2], wv[ks * 4 + 3]);
        bf16x8 pf = *reinterpret_cast<bf16x8*>(&u);
        const int pc = ((ks * 2 + hi) ^ swz) << 3;
        bf16x8 vf0 = *reinterpret_cast<const bf16x8*>(&Vl[cur][l31 * 64 + pc]);
        bf16x8 vf1 = *reinterpret_cast<const bf16x8*>(&Vl[cur][(l31 + 32) * 64 + pc]);
        accO0 = __builtin_amdgcn_mfma_f32_32x32x16_bf16(vf0, pf, accO0, 0, 0, 0);
        accO1 = __builtin_amdgcn_mfma_f32_32x32x16_bf16(vf1, pf, accO1, 0, 0, 0);
      }
    }
    __syncthreads();
  }

  // ---- epilogue: normalize + write O[b][q][h*64+d] ----
  const float inv = 1.0f / lsum;
  bf16* orow = Ob + ((size_t)b * SEQ + qrow) * EMB + h * HD + hi * 4;
#pragma unroll
  for (int rq = 0; rq < 4; ++rq) {
    bf16x4 o0, o1;
#pragma unroll
    for (int i = 0; i < 4; ++i) {
      o0[i] = (bf16)(accO0[rq * 4 + i] * inv);
      o1[i] = (bf16)(accO1[rq * 4 + i] * inv);
    }
    *reinterpret_cast<bf16x4*>(orow + rq * 8) = o0;
    *reinterpret_cast<bf16x4*>(orow + 32 + rq * 8) = o1;
  }
}

// ---------------- launch ----------------
extern "C" void kernel_launch(void* const* d_in, const int* in_sizes, int n_in,
                              void* d_out, int out_size, void* d_ws, size_t ws_size,
                              hipStream_t stream) {
  const float* x    = (const float*)d_in[0];
  const float* Wqkv = (const float*)d_in[1];
  const float* bqkv = (const float*)d_in[2];
  const float* Wout = (const float*)d_in[3];
  const float* bout = (const float*)d_in[4];
  float* out = (float*)d_out;

  char* ws = (char*)d_ws;
  bf16* xb     = (bf16*)(ws);                      // 4096x1024   8 MiB
  bf16* wqkvt  = (bf16*)(ws + 8388608);            // 3072x1024   6 MiB (W_qkv^T)
  bf16* woutt  = (bf16*)(ws + 14680064);           // 1024x1024   2 MiB (W_out^T)
  bf16* Qb     = (bf16*)(ws + 16777216);           // [b][h][s][d] 8 MiB (pre-scaled)
  bf16* Kb     = (bf16*)(ws + 25165824);           // [b][h][s][d] 8 MiB
  bf16* Vtb    = (bf16*)(ws + 33554432);           // [b][h][d][s] 8 MiB
  bf16* attnb  = (bf16*)(ws + 41943040);           // 4096x1024   8 MiB

  const int n1 = 4096 * 1024;
  cvt_f32_bf16<<<(n1 / 4 + 255) / 256, 256, 0, stream>>>(x, xb, n1);
  dim3 tb(32, 8);
  transpose_cvt<<<dim3(3072 / 32, 1024 / 32), tb, 0, stream>>>(Wqkv, wqkvt, 1024, 3072);
  transpose_cvt<<<dim3(1024 / 32, 1024 / 32), tb, 0, stream>>>(Wout, woutt, 1024, 1024);

  dim3 g1(3072 / BN, 4096 / BM);   // 24 x 32
  gemm_bf16<<<g1, 256, 0, stream>>>(xb, wqkvt, bqkv, 4096, 3072, 1024,
                                    nullptr, Qb, Kb, Vtb, 1);

  attn_fwd<<<512, 256, 0, stream>>>(Qb, Kb, Vtb, attnb);

  dim3 g2(1024 / BN, 4096 / BM);   // 8 x 32
  gemm_bf16<<<g2, 256, 0, stream>>>(attnb, woutt, bout, 4096, 1024, 1024,
                                    out, nullptr, nullptr, nullptr, 0);
}